// Round 6
// baseline (890.828 us; speedup 1.0000x reference)
//
#include <hip/hip_runtime.h>

typedef float f32x4 __attribute__((ext_vector_type(4)));
typedef short s16x8 __attribute__((ext_vector_type(8)));
typedef unsigned uint4v __attribute__((ext_vector_type(4)));

#define HH   768
#define SS   256
#define GR   8     // row groups (16 rows each); g = blockIdx & 7
#define GP   24    // col blocks per group; p = blockIdx >> 3
#define NROW 128
#define LDP  776   // LDS row pitch (shorts); 1552B = 16B-aligned rows
#define PP   68    // partials row pitch (floats)

__device__ __forceinline__ unsigned short f2bf(float f) {
  unsigned int u = __float_as_uint(f);
  u += 0x7FFFu + ((u >> 16) & 1u);          // RTNE
  return (unsigned short)(u >> 16);
}
__device__ __forceinline__ float bf2f(unsigned short s) {
  return __uint_as_float(((unsigned int)s) << 16);
}
__device__ __forceinline__ float sigm(float v) { return 1.0f / (1.0f + __expf(-v)); }
__device__ __forceinline__ float tanhf_(float v) {
  return 1.0f - 2.0f / (__expf(2.0f * v) + 1.0f);
}

// 192 blocks x 512 threads (8 waves, 2/SIMD via launch_bounds(512,2)).
// Static roles: g = blockIdx&7 (rows [16g,16g+16)), p = blockIdx>>3 (hidden
// cols [32p,32p+32)); gate cols permuted col = hcol*4 + gate.
// Wave w: colh = w&1 (64-gate-col half), ks = w>>1 (6-kt slice of K).
// R12 (kept, WIN 968->830): h transported bf16-only; GEMM h_hi*(W_hi+W_lo),
// weights stay ~f32 via register-resident Blo. absmax 1.2e-4.
// R13 (this round): fast-path barrier moved to the LOCAL XCD TCC.
//   Why R9 hung: its poll was a plain sc0 LOAD -> if sc0 doesn't bypass L1,
//   the line sticks stale in L1 -> infinite spin. Fix: poll with a returning
//   RMW (fetch_add 0) — vector atomics execute at the TCC unconditionally,
//   never served by L1. Arrival fetch_add(1) + poll fetch_add(0), BOTH
//   workgroup-scope (no sc1 => local TCC; vote proves all 24 share it).
//   tid0-only poller + trailing __syncthreads = proven R6 structure; only
//   the two memory ops changed. s_sleep(2) keeps 24 pollers under the TCC
//   atomic service rate. Slow path: R6 agent-scope barrier verbatim.
// Transport: R6-proven — XCC_ID vote gating write-through stores + plain
// loads in the XCD L2 (3 parities defeat stale L1).
// Dead ends (do not revisit): R10 direct-L2 A-frags (exposed latency chains,
// -32%), R11 split-phase staging + sleepless poll (-18%), R8 flag-poll.
__global__ void __launch_bounds__(512, 2) lstm_persistent(
    const float* __restrict__ xin, const float* __restrict__ h0,
    const float* __restrict__ c0,
    const float* __restrict__ Wi, const float* __restrict__ bi,
    const float* __restrict__ Wf, const float* __restrict__ bfv,
    const float* __restrict__ Wc, const float* __restrict__ bc,
    const float* __restrict__ Wo, const float* __restrict__ bo,
    const float* __restrict__ Wout, const float* __restrict__ bout,
    float* __restrict__ out,
    unsigned short* __restrict__ hhi0, unsigned short* __restrict__ hhi1,
    unsigned short* __restrict__ hhi2,
    unsigned short* __restrict__ hlo0, unsigned short* __restrict__ hlo1,
    unsigned short* __restrict__ hlo2,
    unsigned* __restrict__ bar)
{
  const int tid = threadIdx.x, wave = tid >> 6, lane = tid & 63;
  const int l15 = lane & 15, quad = lane >> 4;
  const int g = blockIdx.x & 7, p = blockIdx.x >> 3;
  const int row_base = g * 16, hcol_base = p * 32;
  const int colh = wave & 1, ks = wave >> 1;   // col-half / kt-slice

  __shared__ __align__(16) unsigned short lds_hi[16 * LDP];
  __shared__ __align__(16) float part[2][4][16][PP];   // [colh][ks][row][col64]
  __shared__ float bw_b[128], bw_w[128];               // bias / x-weight per col
  __shared__ float c_lds[16][33];
  __shared__ float x_lds[16];
  __shared__ int s_fast;

  unsigned* ctr = bar + g * 64;              // step barrier (256B-spaced)
  unsigned* rdy = bar + 512 + g * 16;        // rendezvous counter
  unsigned* ids = bar + 640 + g * 32;        // 24 published XCC_IDs

  // ---- one-time vote (tid0): all 24 members on one XCD? [R6-proven] ----
  if (tid == 0) {
    const unsigned my = (__builtin_amdgcn_s_getreg(20 | (3 << 11)) & 15u) + 1u;
    __hip_atomic_store(ids + p, my, __ATOMIC_RELAXED, __HIP_MEMORY_SCOPE_AGENT);
    __hip_atomic_fetch_add(rdy, 1u, __ATOMIC_RELEASE, __HIP_MEMORY_SCOPE_AGENT);
    while (__hip_atomic_load(rdy, __ATOMIC_ACQUIRE, __HIP_MEMORY_SCOPE_AGENT)
           < (unsigned)GP)
      __builtin_amdgcn_s_sleep(8);
    int ok = 1;
    for (int q = 0; q < GP; ++q)
      ok &= (__hip_atomic_load(ids + q, __ATOMIC_RELAXED,
                               __HIP_MEMORY_SCOPE_AGENT) == my);
    s_fast = ok;
  }

  // ---- one-time: weights -> bf16 hi/lo B-fragments (n=lane&15, k=quad*8+j) --
  // Blo (W_lo) kept in registers: weights remain ~f32-accurate at zero
  // transport cost. Only the h-side lo is dropped (R12).
  s16x8 Bhi[6][4], Blo[6][4];
#pragma unroll
  for (int n = 0; n < 4; ++n) {
    const int col = p * 128 + colh * 64 + n * 16 + l15;  // permuted gate col
    const int gg = col & 3, hc = col >> 2;
    const float* W = (gg == 0) ? Wi : (gg == 1) ? Wf : (gg == 2) ? Wc : Wo;
#pragma unroll
    for (int ktl = 0; ktl < 6; ++ktl) {
      const int kt = ks * 6 + ktl;
      s16x8 vh, vl;
#pragma unroll
      for (int j = 0; j < 8; ++j) {
        const int k = kt * 32 + quad * 8 + j;
        const float w = W[(1 + k) * HH + hc];
        const unsigned short hi = f2bf(w);
        vh[j] = (short)hi;
        vl[j] = (short)f2bf(w - bf2f(hi));
      }
      Bhi[ktl][n] = vh; Blo[ktl][n] = vl;
    }
  }

  // ---- one-time: bias + x-weight tables -> LDS (per permuted gate col) ----
  if (tid < 128) {
    const int gg = tid & 3;
    const int hc = p * 32 + (tid >> 2);
    const float* W  = (gg == 0) ? Wi : (gg == 1) ? Wf : (gg == 2) ? Wc : Wo;
    const float* bb = (gg == 0) ? bi : (gg == 1) ? bfv : (gg == 2) ? bc : bo;
    bw_b[tid] = bb[hc];
    bw_w[tid] = W[hc];                       // W row 0 = x weight (exact fp32)
  }

  // ---- init: c->LDS; h0 -> parity-0 hi buffer (agent stores) ----
  if (tid < 256) {
    const int lr = tid >> 4, lc = (tid & 15) * 2;
    const int gidx = (row_base + lr) * HH + hcol_base + lc;
    const float ha = h0[gidx], hb = h0[gidx + 1];
    c_lds[lr][lc]     = c0[gidx];
    c_lds[lr][lc + 1] = c0[gidx + 1];
    const unsigned short ha_hi = f2bf(ha), hb_hi = f2bf(hb);
    __hip_atomic_store((unsigned*)hhi0 + (gidx >> 1),
                       (unsigned)ha_hi | ((unsigned)hb_hi << 16),
                       __ATOMIC_RELAXED, __HIP_MEMORY_SCOPE_AGENT);
    if (tid < 16) {
      const int row = row_base + tid;
      x_lds[tid] = xin[(row >> 1) * (SS * 2) + (row & 1)];   // t = 0
    }
  }
  __syncthreads();                           // s_fast + LDS init visible
  const bool fast = (s_fast != 0);
  unsigned bars = 0;

  // Opaque zero (keeps the poll RMW a real atomicrmw; no const-fold to load).
  unsigned zerov = 0;
  asm volatile("" : "+v"(zerov));

  // Step barrier. fast: local-TCC RMW arrival + RMW poll (atomics bypass L1
  // architecturally — no stale-spin, unlike R9's sc0 load). slow: R6 agent.
  auto gbar = [&]() {
    __builtin_amdgcn_s_waitcnt(0);
    __syncthreads();
    if (tid == 0) {
      ++bars;
      const unsigned want = (unsigned)GP * bars;
      if (fast) {
        __hip_atomic_fetch_add(ctr, 1u, __ATOMIC_RELAXED,
                               __HIP_MEMORY_SCOPE_WORKGROUP);
        while (__hip_atomic_fetch_add(ctr, zerov, __ATOMIC_RELAXED,
                                      __HIP_MEMORY_SCOPE_WORKGROUP) < want)
          __builtin_amdgcn_s_sleep(2);
      } else {
        __hip_atomic_fetch_add(ctr, 1u, __ATOMIC_RELAXED, __HIP_MEMORY_SCOPE_AGENT);
        while (__hip_atomic_load(ctr, __ATOMIC_RELAXED, __HIP_MEMORY_SCOPE_AGENT) < want)
          __builtin_amdgcn_s_sleep(1);
      }
    }
    __syncthreads();
  };

  gbar();                                    // h0/c0 published

  const unsigned short* hbhi[3] = {hhi0, hhi1, hhi2};
  unsigned short* wbhi[3] = {hhi0, hhi1, hhi2};

  const int frag_off = l15 * LDP + quad * 8; // A-frag LDS offset (shorts)
  const int lr_c = tid >> 5, lc_c = tid & 31;        // elementwise cell
  const int ch_c = lc_c >> 4, c4_c = (lc_c & 15) * 4;
  int cur = 0;

  for (int t = 0; t < SS; ++t) {
    const int nxt = (cur == 2) ? 0 : cur + 1;
    const unsigned short* rhi = hbhi[cur];
    unsigned short* whi = wbhi[nxt];

    // ---- stage group h-slice (16x768 hi) into LDS ----
    if (fast) {                              // plain 16B loads from XCD L2
      const uint4v* rh = (const uint4v*)(rhi + row_base * HH);
      uint4v hv[3];
#pragma unroll
      for (int i = 0; i < 3; ++i) {
        const int gi = i * 512 + tid;        // u128 idx in [0,1536)
        hv[i] = rh[gi];
      }
#pragma unroll
      for (int i = 0; i < 3; ++i) {
        const int gi = i * 512 + tid;
        const int rr = gi / 96, cc = (gi - rr * 96) * 8;
        *(uint4v*)&lds_hi[rr * LDP + cc] = hv[i];
      }
    } else {                                 // agent-scope (MALL) loads
      const int u64_base = row_base * 192;
#pragma unroll
      for (int i = 0; i < 6; ++i) {
        const int gi = i * 512 + tid;        // u64 idx in [0,3072)
        const int rr = gi / 192, cc = (gi - rr * 192) * 4;
        const unsigned long long vh = __hip_atomic_load(
            (unsigned long long*)rhi + u64_base + gi, __ATOMIC_RELAXED, __HIP_MEMORY_SCOPE_AGENT);
        *(unsigned long long*)&lds_hi[rr * LDP + cc] = vh;
      }
    }
    __syncthreads();

    // ---- GEMM: wave (colh,ks): 6kt x 4n, 2 MFMA/(ktl,n): h_hi*(W_hi+W_lo) --
    f32x4 acc[4] = {{0,0,0,0},{0,0,0,0},{0,0,0,0},{0,0,0,0}};
#pragma unroll
    for (int ktl = 0; ktl < 6; ++ktl) {
      const int kt = ks * 6 + ktl;
      const s16x8 ah = *(const s16x8*)&lds_hi[frag_off + kt * 32];
#pragma unroll
      for (int n = 0; n < 4; ++n) {
        acc[n] = __builtin_amdgcn_mfma_f32_16x16x32_bf16(ah, Bhi[ktl][n], acc[n], 0, 0, 0);
        acc[n] = __builtin_amdgcn_mfma_f32_16x16x32_bf16(ah, Blo[ktl][n], acc[n], 0, 0, 0);
      }
    }

    // ---- partial write: C/D layout col=l15, row=quad*4+reg ----
#pragma unroll
    for (int n = 0; n < 4; ++n)
#pragma unroll
      for (int reg = 0; reg < 4; ++reg)
        part[colh][ks][quad * 4 + reg][n * 16 + l15] = acc[n][reg];
    __syncthreads();

    // ---- reduce over ks + bias + x*w0; elementwise; h store (1 cell/thr) --
    {
      const f32x4 s0 = *(const f32x4*)&part[ch_c][0][lr_c][c4_c];
      const f32x4 s1 = *(const f32x4*)&part[ch_c][1][lr_c][c4_c];
      const f32x4 s2 = *(const f32x4*)&part[ch_c][2][lr_c][c4_c];
      const f32x4 s3 = *(const f32x4*)&part[ch_c][3][lr_c][c4_c];
      const f32x4 bq = *(const f32x4*)&bw_b[lc_c * 4];
      const f32x4 wq = *(const f32x4*)&bw_w[lc_c * 4];
      const float xv = x_lds[lr_c];
      f32x4 gv = (s0 + s1) + (s2 + s3);
#pragma unroll
      for (int j = 0; j < 4; ++j) gv[j] += bq[j] + xv * wq[j];

      float cc = c_lds[lr_c][lc_c];
      cc = sigm(gv[1]) * cc + sigm(gv[0]) * tanhf_(gv[2]);
      const float hh = gv[3] * tanhf_(cc);   // no sigmoid on o-gate (ref)
      c_lds[lr_c][lc_c] = cc;

      const unsigned short mhi = f2bf(hh);
      const unsigned ohi = (unsigned)__shfl_down((int)(unsigned)mhi, 1, 64);
      if ((tid & 1) == 0) {                  // lc_c even; neighbor = lc_c+1
        const int gidx = (row_base + lr_c) * HH + hcol_base + lc_c;
        const unsigned ph = (unsigned)mhi | (ohi << 16);
        if (fast) {                          // write-through L1 -> XCD L2
          ((unsigned*)whi)[gidx >> 1] = ph;
        } else {
          __hip_atomic_store((unsigned*)whi + (gidx >> 1), ph, __ATOMIC_RELAXED, __HIP_MEMORY_SCOPE_AGENT);
        }
      }
      if (tid < 16 && t + 1 < SS) {
        const int row = row_base + tid;
        x_lds[tid] = xin[(row >> 1) * (SS * 2) + (t + 1) * 2 + (row & 1)];
      }
    }
    gbar();
    cur = nxt;
  }

  // ---- output projection: final h in parity cur = 256%3 = 1 ----
  if (p == 0 && tid < 256) {
    const unsigned short* fhi = hbhi[cur];
    const int rloc = tid >> 4, s = tid & 15;
    const int row = row_base + rloc;
    float sum = 0.0f;
#pragma unroll
    for (int i = 0; i < 12; ++i) {
      const int u = row * 192 + s * 12 + i;  // u64 idx; k0 = s*48 + i*4
      unsigned long long vh;
      if (fast) {                            // fresh in this XCD's L2
        vh = *((const unsigned long long*)fhi + u);
      } else {
        vh = __hip_atomic_load((unsigned long long*)fhi + u, __ATOMIC_RELAXED, __HIP_MEMORY_SCOPE_AGENT);
      }
#pragma unroll
      for (int j = 0; j < 4; ++j) {
        const float h = bf2f((unsigned short)(vh >> (16 * j)));
        sum += h * Wout[s * 48 + i * 4 + j];
      }
    }
#pragma unroll
    for (int off = 8; off; off >>= 1) sum += __shfl_down(sum, off, 16);
    if (s == 0) out[row] = sum + bout[0];
  }
}

extern "C" void kernel_launch(void* const* d_in, const int* in_sizes, int n_in,
                              void* d_out, int out_size, void* d_ws, size_t ws_size,
                              hipStream_t stream) {
  const float* xin  = (const float*)d_in[0];
  const float* h0   = (const float*)d_in[1];
  const float* c0   = (const float*)d_in[2];
  const float* Wi   = (const float*)d_in[3];
  const float* bi   = (const float*)d_in[4];
  const float* Wf   = (const float*)d_in[5];
  const float* bfv  = (const float*)d_in[6];
  const float* Wc   = (const float*)d_in[7];
  const float* bc   = (const float*)d_in[8];
  const float* Wo   = (const float*)d_in[9];
  const float* bo   = (const float*)d_in[10];
  const float* Wout = (const float*)d_in[11];
  const float* bout = (const float*)d_in[12];
  float* out = (float*)d_out;

  char* ws = (char*)d_ws;
  const size_t HB = (size_t)NROW * HH * sizeof(unsigned short);  // 196608
  unsigned short* hhi0 = (unsigned short*)(ws);
  unsigned short* hhi1 = (unsigned short*)(ws + HB);
  unsigned short* hhi2 = (unsigned short*)(ws + 2 * HB);
  unsigned short* hlo0 = (unsigned short*)(ws + 3 * HB);
  unsigned short* hlo1 = (unsigned short*)(ws + 4 * HB);
  unsigned short* hlo2 = (unsigned short*)(ws + 5 * HB);
  unsigned*       bar  = (unsigned*)(ws + 6 * HB);

  hipMemsetAsync(bar, 0, 4096, stream);    // zero barrier/rendezvous counters

  (void)in_sizes; (void)n_in; (void)out_size; (void)ws_size;
  hipLaunchKernelGGL(lstm_persistent, dim3(GR * GP), dim3(512), 0, stream,
                     xin, h0, c0, Wi, bi, Wf, bfv, Wc, bc, Wo, bo,
                     Wout, bout, out, hhi0, hhi1, hhi2, hlo0, hlo1, hlo2, bar);
}

// Round 7
// 821.571 us; speedup vs baseline: 1.0843x; 1.0843x over previous
//
#include <hip/hip_runtime.h>

typedef float f32x4 __attribute__((ext_vector_type(4)));
typedef short s16x8 __attribute__((ext_vector_type(8)));
typedef unsigned uint4v __attribute__((ext_vector_type(4)));

#define HH   768
#define HHP  776   // h-buffer row pitch in shorts (GLOBAL and LDS identical)
#define SS   256
#define GR   8     // row groups (16 rows each); g = blockIdx & 7
#define GP   24    // col blocks per group; p = blockIdx >> 3
#define NROW 128
#define LDP  776   // LDS row pitch (shorts); 1552B = 16B-aligned rows
#define PP   68    // partials row pitch (floats)

__device__ __forceinline__ unsigned short f2bf(float f) {
  unsigned int u = __float_as_uint(f);
  u += 0x7FFFu + ((u >> 16) & 1u);          // RTNE
  return (unsigned short)(u >> 16);
}
__device__ __forceinline__ float bf2f(unsigned short s) {
  return __uint_as_float(((unsigned int)s) << 16);
}
__device__ __forceinline__ float sigm(float v) { return 1.0f / (1.0f + __expf(-v)); }
__device__ __forceinline__ float tanhf_(float v) {
  return 1.0f - 2.0f / (__expf(2.0f * v) + 1.0f);
}
// async global->LDS, 16B per lane; dest = wave-uniform base + lane*16 (HW).
__device__ __forceinline__ void gll16(const void* gp, void* lp) {
  __builtin_amdgcn_global_load_lds(
      (const __attribute__((address_space(1))) unsigned*)gp,
      (__attribute__((address_space(3))) unsigned*)lp, 16, 0, 0);
}

// 192 blocks x 512 threads (8 waves, 2/SIMD via launch_bounds(512,2)).
// Static roles: g = blockIdx&7 (rows [16g,16g+16)), p = blockIdx>>3 (hidden
// cols [32p,32p+32)); gate cols permuted col = hcol*4 + gate.
// Wave w: colh = w&1 (64-gate-col half), ks = w>>1 (6-kt slice of K).
// R12 (kept, WIN 968->830): h transported bf16-only; GEMM h_hi*(W_hi+W_lo),
// weights ~f32 via register-resident Blo. absmax 1.2e-4.
// R14 (this round): staging via __builtin_amdgcn_global_load_lds width=16.
//   h buffers now PITCH-776 in global (= LDS pitch) so staging is an
//   identity copy: 1552 u128 = 3 wave-issues/thread + 16-thread plain tail.
//   Removes the in-thread vmcnt stall + ds_write issue of the register
//   round-trip (compiler drains vmcnt at the pre-GEMM __syncthreads).
//   L1-staleness argument unchanged (same lines, same L1 path, 3 parities).
// Barrier: R6-proven agent-scope counter VERBATIM. Closed dead ends (do not
// revisit): R8 flag-poll, R9 sc0-load poll (hang), R13 local RMW-poll (+60us),
// R10 direct-L2 A-frags (-32%), R11 split-phase staging (-18%).
__global__ void __launch_bounds__(512, 2) lstm_persistent(
    const float* __restrict__ xin, const float* __restrict__ h0,
    const float* __restrict__ c0,
    const float* __restrict__ Wi, const float* __restrict__ bi,
    const float* __restrict__ Wf, const float* __restrict__ bfv,
    const float* __restrict__ Wc, const float* __restrict__ bc,
    const float* __restrict__ Wo, const float* __restrict__ bo,
    const float* __restrict__ Wout, const float* __restrict__ bout,
    float* __restrict__ out,
    unsigned short* __restrict__ hhi0, unsigned short* __restrict__ hhi1,
    unsigned short* __restrict__ hhi2,
    unsigned short* __restrict__ hlo0, unsigned short* __restrict__ hlo1,
    unsigned short* __restrict__ hlo2,
    unsigned* __restrict__ bar)
{
  const int tid = threadIdx.x, wave = tid >> 6, lane = tid & 63;
  const int l15 = lane & 15, quad = lane >> 4;
  const int g = blockIdx.x & 7, p = blockIdx.x >> 3;
  const int row_base = g * 16, hcol_base = p * 32;
  const int colh = wave & 1, ks = wave >> 1;   // col-half / kt-slice

  __shared__ __align__(16) unsigned short lds_hi[16 * LDP];
  __shared__ __align__(16) float part[2][4][16][PP];   // [colh][ks][row][col64]
  __shared__ float bw_b[128], bw_w[128];               // bias / x-weight per col
  __shared__ float c_lds[16][33];
  __shared__ float x_lds[16];
  __shared__ int s_fast;

  unsigned* ctr = bar + g * 64;              // step barrier (256B-spaced)
  unsigned* rdy = bar + 512 + g * 16;        // rendezvous counter
  unsigned* ids = bar + 640 + g * 32;        // 24 published XCC_IDs

  // ---- one-time vote (tid0): all 24 members on one XCD? [R6-proven] ----
  if (tid == 0) {
    const unsigned my = (__builtin_amdgcn_s_getreg(20 | (3 << 11)) & 15u) + 1u;
    __hip_atomic_store(ids + p, my, __ATOMIC_RELAXED, __HIP_MEMORY_SCOPE_AGENT);
    __hip_atomic_fetch_add(rdy, 1u, __ATOMIC_RELEASE, __HIP_MEMORY_SCOPE_AGENT);
    while (__hip_atomic_load(rdy, __ATOMIC_ACQUIRE, __HIP_MEMORY_SCOPE_AGENT)
           < (unsigned)GP)
      __builtin_amdgcn_s_sleep(8);
    int ok = 1;
    for (int q = 0; q < GP; ++q)
      ok &= (__hip_atomic_load(ids + q, __ATOMIC_RELAXED,
                               __HIP_MEMORY_SCOPE_AGENT) == my);
    s_fast = ok;
  }

  // ---- one-time: weights -> bf16 hi/lo B-fragments (n=lane&15, k=quad*8+j) --
  // Blo (W_lo) kept in registers: weights remain ~f32-accurate at zero
  // transport cost. Only the h-side lo is dropped (R12).
  s16x8 Bhi[6][4], Blo[6][4];
#pragma unroll
  for (int n = 0; n < 4; ++n) {
    const int col = p * 128 + colh * 64 + n * 16 + l15;  // permuted gate col
    const int gg = col & 3, hc = col >> 2;
    const float* W = (gg == 0) ? Wi : (gg == 1) ? Wf : (gg == 2) ? Wc : Wo;
#pragma unroll
    for (int ktl = 0; ktl < 6; ++ktl) {
      const int kt = ks * 6 + ktl;
      s16x8 vh, vl;
#pragma unroll
      for (int j = 0; j < 8; ++j) {
        const int k = kt * 32 + quad * 8 + j;
        const float w = W[(1 + k) * HH + hc];
        const unsigned short hi = f2bf(w);
        vh[j] = (short)hi;
        vl[j] = (short)f2bf(w - bf2f(hi));
      }
      Bhi[ktl][n] = vh; Blo[ktl][n] = vl;
    }
  }

  // ---- one-time: bias + x-weight tables -> LDS (per permuted gate col) ----
  if (tid < 128) {
    const int gg = tid & 3;
    const int hc = p * 32 + (tid >> 2);
    const float* W  = (gg == 0) ? Wi : (gg == 1) ? Wf : (gg == 2) ? Wc : Wo;
    const float* bb = (gg == 0) ? bi : (gg == 1) ? bfv : (gg == 2) ? bc : bo;
    bw_b[tid] = bb[hc];
    bw_w[tid] = W[hc];                       // W row 0 = x weight (exact fp32)
  }

  // ---- init: c->LDS; h0 -> parity-0 hi buffer (agent stores, pitch 776) --
  if (tid < 256) {
    const int lr = tid >> 4, lc = (tid & 15) * 2;
    const int gidx = (row_base + lr) * HH + hcol_base + lc;    // input (768)
    const int sidx = (row_base + lr) * HHP + hcol_base + lc;   // buffer (776)
    const float ha = h0[gidx], hb = h0[gidx + 1];
    c_lds[lr][lc]     = c0[gidx];
    c_lds[lr][lc + 1] = c0[gidx + 1];
    const unsigned short ha_hi = f2bf(ha), hb_hi = f2bf(hb);
    __hip_atomic_store((unsigned*)hhi0 + (sidx >> 1),
                       (unsigned)ha_hi | ((unsigned)hb_hi << 16),
                       __ATOMIC_RELAXED, __HIP_MEMORY_SCOPE_AGENT);
    if (tid < 16) {
      const int row = row_base + tid;
      x_lds[tid] = xin[(row >> 1) * (SS * 2) + (row & 1)];   // t = 0
    }
  }
  __syncthreads();                           // s_fast + LDS init visible
  const bool fast = (s_fast != 0);
  unsigned bars = 0;

  // Agent-scope counter barrier (R3/R6-proven; R8/R9/R13 variants failed).
  auto gbar = [&]() {
    __builtin_amdgcn_s_waitcnt(0);
    __syncthreads();
    if (tid == 0) {
      ++bars;
      __hip_atomic_fetch_add(ctr, 1u, __ATOMIC_RELAXED, __HIP_MEMORY_SCOPE_AGENT);
      const unsigned want = (unsigned)GP * bars;
      while (__hip_atomic_load(ctr, __ATOMIC_RELAXED, __HIP_MEMORY_SCOPE_AGENT) < want)
        __builtin_amdgcn_s_sleep(1);
    }
    __syncthreads();
  };

  gbar();                                    // h0/c0 published

  const unsigned short* hbhi[3] = {hhi0, hhi1, hhi2};
  unsigned short* wbhi[3] = {hhi0, hhi1, hhi2};

  const int frag_off = l15 * LDP + quad * 8; // A-frag LDS offset (shorts)
  const int lr_c = tid >> 5, lc_c = tid & 31;        // elementwise cell
  const int ch_c = lc_c >> 4, c4_c = (lc_c & 15) * 4;
  const int wbase = wave * 64;               // wave-uniform lane base
  int cur = 0;

  for (int t = 0; t < SS; ++t) {
    const int nxt = (cur == 2) ? 0 : cur + 1;
    const unsigned short* rhi = hbhi[cur];
    unsigned short* whi = wbhi[nxt];

    // ---- stage group h-slice: identity copy 16 x 776 shorts (24832B) ----
    if (fast) {                              // async global->LDS, no VGPR trip
      const unsigned short* src = rhi + row_base * HHP;
#pragma unroll
      for (int i = 0; i < 3; ++i) {
        const int gi = i * 512 + tid;        // u128 idx (per-lane global src)
        gll16(src + gi * 8, &lds_hi[(i * 512 + wbase) * 8]);
      }
      if (tid < 16) {                        // tail u128s 1536..1551 (plain)
        const uint4v v = *(const uint4v*)(src + (1536 + tid) * 8);
        *(uint4v*)&lds_hi[(1536 + tid) * 8] = v;
      }
    } else {                                 // agent-scope (MALL) identity copy
      const unsigned long long* src64 =
          (const unsigned long long*)rhi + row_base * (HHP / 4);
#pragma unroll
      for (int i = 0; i < 6; ++i) {
        const int gi = i * 512 + tid;        // u64 idx in [0,3072)
        const unsigned long long vh = __hip_atomic_load(
            src64 + gi, __ATOMIC_RELAXED, __HIP_MEMORY_SCOPE_AGENT);
        *(unsigned long long*)&lds_hi[gi * 4] = vh;
      }
      if (tid < 32) {                        // tail u64s 3072..3103
        const int gi = 3072 + tid;
        const unsigned long long vh = __hip_atomic_load(
            src64 + gi, __ATOMIC_RELAXED, __HIP_MEMORY_SCOPE_AGENT);
        *(unsigned long long*)&lds_hi[gi * 4] = vh;
      }
    }
    __syncthreads();                         // drains vmcnt (gll) + lgkm

    // ---- GEMM: wave (colh,ks): 6kt x 4n, 2 MFMA/(ktl,n): h_hi*(W_hi+W_lo) --
    f32x4 acc[4] = {{0,0,0,0},{0,0,0,0},{0,0,0,0},{0,0,0,0}};
#pragma unroll
    for (int ktl = 0; ktl < 6; ++ktl) {
      const int kt = ks * 6 + ktl;
      const s16x8 ah = *(const s16x8*)&lds_hi[frag_off + kt * 32];
#pragma unroll
      for (int n = 0; n < 4; ++n) {
        acc[n] = __builtin_amdgcn_mfma_f32_16x16x32_bf16(ah, Bhi[ktl][n], acc[n], 0, 0, 0);
        acc[n] = __builtin_amdgcn_mfma_f32_16x16x32_bf16(ah, Blo[ktl][n], acc[n], 0, 0, 0);
      }
    }

    // ---- partial write: C/D layout col=l15, row=quad*4+reg ----
#pragma unroll
    for (int n = 0; n < 4; ++n)
#pragma unroll
      for (int reg = 0; reg < 4; ++reg)
        part[colh][ks][quad * 4 + reg][n * 16 + l15] = acc[n][reg];
    __syncthreads();

    // ---- reduce over ks + bias + x*w0; elementwise; h store (1 cell/thr) --
    {
      const f32x4 s0 = *(const f32x4*)&part[ch_c][0][lr_c][c4_c];
      const f32x4 s1 = *(const f32x4*)&part[ch_c][1][lr_c][c4_c];
      const f32x4 s2 = *(const f32x4*)&part[ch_c][2][lr_c][c4_c];
      const f32x4 s3 = *(const f32x4*)&part[ch_c][3][lr_c][c4_c];
      const f32x4 bq = *(const f32x4*)&bw_b[lc_c * 4];
      const f32x4 wq = *(const f32x4*)&bw_w[lc_c * 4];
      const float xv = x_lds[lr_c];
      f32x4 gv = (s0 + s1) + (s2 + s3);
#pragma unroll
      for (int j = 0; j < 4; ++j) gv[j] += bq[j] + xv * wq[j];

      float cc = c_lds[lr_c][lc_c];
      cc = sigm(gv[1]) * cc + sigm(gv[0]) * tanhf_(gv[2]);
      const float hh = gv[3] * tanhf_(cc);   // no sigmoid on o-gate (ref)
      c_lds[lr_c][lc_c] = cc;

      const unsigned short mhi = f2bf(hh);
      const unsigned ohi = (unsigned)__shfl_down((int)(unsigned)mhi, 1, 64);
      if ((tid & 1) == 0) {                  // lc_c even; neighbor = lc_c+1
        const int sidx = (row_base + lr_c) * HHP + hcol_base + lc_c;
        const unsigned ph = (unsigned)mhi | (ohi << 16);
        if (fast) {                          // write-through L1 -> XCD L2
          ((unsigned*)whi)[sidx >> 1] = ph;
        } else {
          __hip_atomic_store((unsigned*)whi + (sidx >> 1), ph, __ATOMIC_RELAXED, __HIP_MEMORY_SCOPE_AGENT);
        }
      }
      if (tid < 16 && t + 1 < SS) {
        const int row = row_base + tid;
        x_lds[tid] = xin[(row >> 1) * (SS * 2) + (t + 1) * 2 + (row & 1)];
      }
    }
    gbar();
    cur = nxt;
  }

  // ---- output projection: final h in parity cur = 256%3 = 1 ----
  if (p == 0 && tid < 256) {
    const unsigned short* fhi = hbhi[cur];
    const int rloc = tid >> 4, s = tid & 15;
    const int row = row_base + rloc;
    float sum = 0.0f;
#pragma unroll
    for (int i = 0; i < 12; ++i) {
      const int u = row * (HHP / 4) + s * 12 + i;  // u64 idx; k0 = s*48 + i*4
      unsigned long long vh;
      if (fast) {                            // fresh in this XCD's L2
        vh = *((const unsigned long long*)fhi + u);
      } else {
        vh = __hip_atomic_load((unsigned long long*)fhi + u, __ATOMIC_RELAXED, __HIP_MEMORY_SCOPE_AGENT);
      }
#pragma unroll
      for (int j = 0; j < 4; ++j) {
        const float h = bf2f((unsigned short)(vh >> (16 * j)));
        sum += h * Wout[s * 48 + i * 4 + j];
      }
    }
#pragma unroll
    for (int off = 8; off; off >>= 1) sum += __shfl_down(sum, off, 16);
    if (s == 0) out[row] = sum + bout[0];
  }
}

extern "C" void kernel_launch(void* const* d_in, const int* in_sizes, int n_in,
                              void* d_out, int out_size, void* d_ws, size_t ws_size,
                              hipStream_t stream) {
  const float* xin  = (const float*)d_in[0];
  const float* h0   = (const float*)d_in[1];
  const float* c0   = (const float*)d_in[2];
  const float* Wi   = (const float*)d_in[3];
  const float* bi   = (const float*)d_in[4];
  const float* Wf   = (const float*)d_in[5];
  const float* bfv  = (const float*)d_in[6];
  const float* Wc   = (const float*)d_in[7];
  const float* bc   = (const float*)d_in[8];
  const float* Wo   = (const float*)d_in[9];
  const float* bo   = (const float*)d_in[10];
  const float* Wout = (const float*)d_in[11];
  const float* bout = (const float*)d_in[12];
  float* out = (float*)d_out;

  char* ws = (char*)d_ws;
  const size_t HB = (size_t)NROW * HHP * sizeof(unsigned short);  // 198656
  unsigned short* hhi0 = (unsigned short*)(ws);
  unsigned short* hhi1 = (unsigned short*)(ws + HB);
  unsigned short* hhi2 = (unsigned short*)(ws + 2 * HB);
  unsigned*       bar  = (unsigned*)(ws + 3 * HB);
  unsigned short* dummy = (unsigned short*)(ws + 3 * HB + 4096);  // unused lo

  hipMemsetAsync(bar, 0, 4096, stream);    // zero barrier/rendezvous counters

  (void)in_sizes; (void)n_in; (void)out_size; (void)ws_size;
  hipLaunchKernelGGL(lstm_persistent, dim3(GR * GP), dim3(512), 0, stream,
                     xin, h0, c0, Wi, bi, Wf, bfv, Wc, bc, Wo, bo,
                     Wout, bout, out, hhi0, hhi1, hhi2, dummy, dummy, dummy, bar);
}

// Round 8
// 687.060 us; speedup vs baseline: 1.2966x; 1.1958x over previous
//
#include <hip/hip_runtime.h>

typedef float f32x4 __attribute__((ext_vector_type(4)));
typedef short s16x8 __attribute__((ext_vector_type(8)));
typedef unsigned uint4v __attribute__((ext_vector_type(4)));

#define HH   768
#define HHP  776   // h-buffer row pitch in shorts (GLOBAL and LDS identical)
#define SS   256
#define GR   8     // row groups (16 rows each); g = blockIdx & 7
#define GP   24    // col blocks per group; p = blockIdx >> 3
#define NROW 128
#define LDP  776   // LDS row pitch (shorts); 1552B = 16B-aligned rows
#define PP   68    // partials row pitch (floats)

__device__ __forceinline__ unsigned short f2bf(float f) {
  unsigned int u = __float_as_uint(f);
  u += 0x7FFFu + ((u >> 16) & 1u);          // RTNE
  return (unsigned short)(u >> 16);
}
__device__ __forceinline__ float bf2f(unsigned short s) {
  return __uint_as_float(((unsigned int)s) << 16);
}
__device__ __forceinline__ float sigm(float v) { return 1.0f / (1.0f + __expf(-v)); }
__device__ __forceinline__ float tanhf_(float v) {
  return 1.0f - 2.0f / (__expf(2.0f * v) + 1.0f);
}
// async global->LDS, 16B per lane; dest = wave-uniform base + lane*16 (HW).
__device__ __forceinline__ void gll16(const void* gp, void* lp) {
  __builtin_amdgcn_global_load_lds(
      (const __attribute__((address_space(1))) unsigned*)gp,
      (__attribute__((address_space(3))) unsigned*)lp, 16, 0, 0);
}

// 192 blocks x 512 threads (8 waves, 2/SIMD via launch_bounds(512,2)).
// Static roles: g = blockIdx&7 (rows [16g,16g+16)), p = blockIdx>>3 (hidden
// cols [32p,32p+32)); gate cols permuted col = hcol*4 + gate.
// Wave w: colh = w&1 (64-gate-col half), ks = w>>1 (6-kt slice of K).
// R12 (WIN 968->830): h transported bf16-only. R14 (neutral, kept): staging
// via global_load_lds w=16, h buffers pitch-776 (identity copy; staging
// round-trip proven off the critical path; conflicts live elsewhere).
// R15 (this round): DROP Blo — single MFMA h_hi*W_hi per (ktl,n), 24 vs 48
// MFMA/wave, halving the MFMA-pipe term (~466->233cy of the ~2900cy step).
// W rounds to bf16: same error scale as R12's h-side rounding (absmax was
// 1.2e-4); predicted absmax 2-5e-4. Frees 96 VGPR (Blo gone).
// Barrier: R6-proven agent-scope counter VERBATIM. Closed dead ends (do not
// revisit): R8 flag-poll, R9 sc0-load poll (hang), R13 local RMW-poll (+60us),
// R10 direct-L2 A-frags (-32%), R11 split-phase staging (-18%), R14 staging
// DMA (neutral).
__global__ void __launch_bounds__(512, 2) lstm_persistent(
    const float* __restrict__ xin, const float* __restrict__ h0,
    const float* __restrict__ c0,
    const float* __restrict__ Wi, const float* __restrict__ bi,
    const float* __restrict__ Wf, const float* __restrict__ bfv,
    const float* __restrict__ Wc, const float* __restrict__ bc,
    const float* __restrict__ Wo, const float* __restrict__ bo,
    const float* __restrict__ Wout, const float* __restrict__ bout,
    float* __restrict__ out,
    unsigned short* __restrict__ hhi0, unsigned short* __restrict__ hhi1,
    unsigned short* __restrict__ hhi2,
    unsigned short* __restrict__ hlo0, unsigned short* __restrict__ hlo1,
    unsigned short* __restrict__ hlo2,
    unsigned* __restrict__ bar)
{
  const int tid = threadIdx.x, wave = tid >> 6, lane = tid & 63;
  const int l15 = lane & 15, quad = lane >> 4;
  const int g = blockIdx.x & 7, p = blockIdx.x >> 3;
  const int row_base = g * 16, hcol_base = p * 32;
  const int colh = wave & 1, ks = wave >> 1;   // col-half / kt-slice

  __shared__ __align__(16) unsigned short lds_hi[16 * LDP];
  __shared__ __align__(16) float part[2][4][16][PP];   // [colh][ks][row][col64]
  __shared__ float bw_b[128], bw_w[128];               // bias / x-weight per col
  __shared__ float c_lds[16][33];
  __shared__ float x_lds[16];
  __shared__ int s_fast;

  unsigned* ctr = bar + g * 64;              // step barrier (256B-spaced)
  unsigned* rdy = bar + 512 + g * 16;        // rendezvous counter
  unsigned* ids = bar + 640 + g * 32;        // 24 published XCC_IDs

  // ---- one-time vote (tid0): all 24 members on one XCD? [R6-proven] ----
  if (tid == 0) {
    const unsigned my = (__builtin_amdgcn_s_getreg(20 | (3 << 11)) & 15u) + 1u;
    __hip_atomic_store(ids + p, my, __ATOMIC_RELAXED, __HIP_MEMORY_SCOPE_AGENT);
    __hip_atomic_fetch_add(rdy, 1u, __ATOMIC_RELEASE, __HIP_MEMORY_SCOPE_AGENT);
    while (__hip_atomic_load(rdy, __ATOMIC_ACQUIRE, __HIP_MEMORY_SCOPE_AGENT)
           < (unsigned)GP)
      __builtin_amdgcn_s_sleep(8);
    int ok = 1;
    for (int q = 0; q < GP; ++q)
      ok &= (__hip_atomic_load(ids + q, __ATOMIC_RELAXED,
                               __HIP_MEMORY_SCOPE_AGENT) == my);
    s_fast = ok;
  }

  // ---- one-time: weights -> bf16 hi B-fragments (n=lane&15, k=quad*8+j) --
  // R15: W transported as single bf16 (Blo dropped; error scale = h-side).
  s16x8 Bhi[6][4];
#pragma unroll
  for (int n = 0; n < 4; ++n) {
    const int col = p * 128 + colh * 64 + n * 16 + l15;  // permuted gate col
    const int gg = col & 3, hc = col >> 2;
    const float* W = (gg == 0) ? Wi : (gg == 1) ? Wf : (gg == 2) ? Wc : Wo;
#pragma unroll
    for (int ktl = 0; ktl < 6; ++ktl) {
      const int kt = ks * 6 + ktl;
      s16x8 vh;
#pragma unroll
      for (int j = 0; j < 8; ++j) {
        const int k = kt * 32 + quad * 8 + j;
        vh[j] = (short)f2bf(W[(1 + k) * HH + hc]);
      }
      Bhi[ktl][n] = vh;
    }
  }

  // ---- one-time: bias + x-weight tables -> LDS (per permuted gate col) ----
  if (tid < 128) {
    const int gg = tid & 3;
    const int hc = p * 32 + (tid >> 2);
    const float* W  = (gg == 0) ? Wi : (gg == 1) ? Wf : (gg == 2) ? Wc : Wo;
    const float* bb = (gg == 0) ? bi : (gg == 1) ? bfv : (gg == 2) ? bc : bo;
    bw_b[tid] = bb[hc];
    bw_w[tid] = W[hc];                       // W row 0 = x weight (exact fp32)
  }

  // ---- init: c->LDS; h0 -> parity-0 hi buffer (agent stores, pitch 776) --
  if (tid < 256) {
    const int lr = tid >> 4, lc = (tid & 15) * 2;
    const int gidx = (row_base + lr) * HH + hcol_base + lc;    // input (768)
    const int sidx = (row_base + lr) * HHP + hcol_base + lc;   // buffer (776)
    const float ha = h0[gidx], hb = h0[gidx + 1];
    c_lds[lr][lc]     = c0[gidx];
    c_lds[lr][lc + 1] = c0[gidx + 1];
    const unsigned short ha_hi = f2bf(ha), hb_hi = f2bf(hb);
    __hip_atomic_store((unsigned*)hhi0 + (sidx >> 1),
                       (unsigned)ha_hi | ((unsigned)hb_hi << 16),
                       __ATOMIC_RELAXED, __HIP_MEMORY_SCOPE_AGENT);
    if (tid < 16) {
      const int row = row_base + tid;
      x_lds[tid] = xin[(row >> 1) * (SS * 2) + (row & 1)];   // t = 0
    }
  }
  __syncthreads();                           // s_fast + LDS init visible
  const bool fast = (s_fast != 0);
  unsigned bars = 0;

  // Agent-scope counter barrier (R3/R6-proven; R8/R9/R13 variants failed).
  auto gbar = [&]() {
    __builtin_amdgcn_s_waitcnt(0);
    __syncthreads();
    if (tid == 0) {
      ++bars;
      __hip_atomic_fetch_add(ctr, 1u, __ATOMIC_RELAXED, __HIP_MEMORY_SCOPE_AGENT);
      const unsigned want = (unsigned)GP * bars;
      while (__hip_atomic_load(ctr, __ATOMIC_RELAXED, __HIP_MEMORY_SCOPE_AGENT) < want)
        __builtin_amdgcn_s_sleep(1);
    }
    __syncthreads();
  };

  gbar();                                    // h0/c0 published

  const unsigned short* hbhi[3] = {hhi0, hhi1, hhi2};
  unsigned short* wbhi[3] = {hhi0, hhi1, hhi2};

  const int frag_off = l15 * LDP + quad * 8; // A-frag LDS offset (shorts)
  const int lr_c = tid >> 5, lc_c = tid & 31;        // elementwise cell
  const int ch_c = lc_c >> 4, c4_c = (lc_c & 15) * 4;
  const int wbase = wave * 64;               // wave-uniform lane base
  int cur = 0;

  for (int t = 0; t < SS; ++t) {
    const int nxt = (cur == 2) ? 0 : cur + 1;
    const unsigned short* rhi = hbhi[cur];
    unsigned short* whi = wbhi[nxt];

    // ---- stage group h-slice: identity copy 16 x 776 shorts (24832B) ----
    if (fast) {                              // async global->LDS, no VGPR trip
      const unsigned short* src = rhi + row_base * HHP;
#pragma unroll
      for (int i = 0; i < 3; ++i) {
        const int gi = i * 512 + tid;        // u128 idx (per-lane global src)
        gll16(src + gi * 8, &lds_hi[(i * 512 + wbase) * 8]);
      }
      if (tid < 16) {                        // tail u128s 1536..1551 (plain)
        const uint4v v = *(const uint4v*)(src + (1536 + tid) * 8);
        *(uint4v*)&lds_hi[(1536 + tid) * 8] = v;
      }
    } else {                                 // agent-scope (MALL) identity copy
      const unsigned long long* src64 =
          (const unsigned long long*)rhi + row_base * (HHP / 4);
#pragma unroll
      for (int i = 0; i < 6; ++i) {
        const int gi = i * 512 + tid;        // u64 idx in [0,3072)
        const unsigned long long vh = __hip_atomic_load(
            src64 + gi, __ATOMIC_RELAXED, __HIP_MEMORY_SCOPE_AGENT);
        *(unsigned long long*)&lds_hi[gi * 4] = vh;
      }
      if (tid < 32) {                        // tail u64s 3072..3103
        const int gi = 3072 + tid;
        const unsigned long long vh = __hip_atomic_load(
            src64 + gi, __ATOMIC_RELAXED, __HIP_MEMORY_SCOPE_AGENT);
        *(unsigned long long*)&lds_hi[gi * 4] = vh;
      }
    }
    __syncthreads();                         // drains vmcnt (gll) + lgkm

    // ---- GEMM: wave (colh,ks): 6kt x 4n, 1 MFMA/(ktl,n): h_hi*W_hi ----
    f32x4 acc[4] = {{0,0,0,0},{0,0,0,0},{0,0,0,0},{0,0,0,0}};
#pragma unroll
    for (int ktl = 0; ktl < 6; ++ktl) {
      const int kt = ks * 6 + ktl;
      const s16x8 ah = *(const s16x8*)&lds_hi[frag_off + kt * 32];
#pragma unroll
      for (int n = 0; n < 4; ++n)
        acc[n] = __builtin_amdgcn_mfma_f32_16x16x32_bf16(ah, Bhi[ktl][n], acc[n], 0, 0, 0);
    }

    // ---- partial write: C/D layout col=l15, row=quad*4+reg ----
#pragma unroll
    for (int n = 0; n < 4; ++n)
#pragma unroll
      for (int reg = 0; reg < 4; ++reg)
        part[colh][ks][quad * 4 + reg][n * 16 + l15] = acc[n][reg];
    __syncthreads();

    // ---- reduce over ks + bias + x*w0; elementwise; h store (1 cell/thr) --
    {
      const f32x4 s0 = *(const f32x4*)&part[ch_c][0][lr_c][c4_c];
      const f32x4 s1 = *(const f32x4*)&part[ch_c][1][lr_c][c4_c];
      const f32x4 s2 = *(const f32x4*)&part[ch_c][2][lr_c][c4_c];
      const f32x4 s3 = *(const f32x4*)&part[ch_c][3][lr_c][c4_c];
      const f32x4 bq = *(const f32x4*)&bw_b[lc_c * 4];
      const f32x4 wq = *(const f32x4*)&bw_w[lc_c * 4];
      const float xv = x_lds[lr_c];
      f32x4 gv = (s0 + s1) + (s2 + s3);
#pragma unroll
      for (int j = 0; j < 4; ++j) gv[j] += bq[j] + xv * wq[j];

      float cc = c_lds[lr_c][lc_c];
      cc = sigm(gv[1]) * cc + sigm(gv[0]) * tanhf_(gv[2]);
      const float hh = gv[3] * tanhf_(cc);   // no sigmoid on o-gate (ref)
      c_lds[lr_c][lc_c] = cc;

      const unsigned short mhi = f2bf(hh);
      const unsigned ohi = (unsigned)__shfl_down((int)(unsigned)mhi, 1, 64);
      if ((tid & 1) == 0) {                  // lc_c even; neighbor = lc_c+1
        const int sidx = (row_base + lr_c) * HHP + hcol_base + lc_c;
        const unsigned ph = (unsigned)mhi | (ohi << 16);
        if (fast) {                          // write-through L1 -> XCD L2
          ((unsigned*)whi)[sidx >> 1] = ph;
        } else {
          __hip_atomic_store((unsigned*)whi + (sidx >> 1), ph, __ATOMIC_RELAXED, __HIP_MEMORY_SCOPE_AGENT);
        }
      }
      if (tid < 16 && t + 1 < SS) {
        const int row = row_base + tid;
        x_lds[tid] = xin[(row >> 1) * (SS * 2) + (t + 1) * 2 + (row & 1)];
      }
    }
    gbar();
    cur = nxt;
  }

  // ---- output projection: final h in parity cur = 256%3 = 1 ----
  if (p == 0 && tid < 256) {
    const unsigned short* fhi = hbhi[cur];
    const int rloc = tid >> 4, s = tid & 15;
    const int row = row_base + rloc;
    float sum = 0.0f;
#pragma unroll
    for (int i = 0; i < 12; ++i) {
      const int u = row * (HHP / 4) + s * 12 + i;  // u64 idx; k0 = s*48 + i*4
      unsigned long long vh;
      if (fast) {                            // fresh in this XCD's L2
        vh = *((const unsigned long long*)fhi + u);
      } else {
        vh = __hip_atomic_load((unsigned long long*)fhi + u, __ATOMIC_RELAXED, __HIP_MEMORY_SCOPE_AGENT);
      }
#pragma unroll
      for (int j = 0; j < 4; ++j) {
        const float h = bf2f((unsigned short)(vh >> (16 * j)));
        sum += h * Wout[s * 48 + i * 4 + j];
      }
    }
#pragma unroll
    for (int off = 8; off; off >>= 1) sum += __shfl_down(sum, off, 16);
    if (s == 0) out[row] = sum + bout[0];
  }
}

extern "C" void kernel_launch(void* const* d_in, const int* in_sizes, int n_in,
                              void* d_out, int out_size, void* d_ws, size_t ws_size,
                              hipStream_t stream) {
  const float* xin  = (const float*)d_in[0];
  const float* h0   = (const float*)d_in[1];
  const float* c0   = (const float*)d_in[2];
  const float* Wi   = (const float*)d_in[3];
  const float* bi   = (const float*)d_in[4];
  const float* Wf   = (const float*)d_in[5];
  const float* bfv  = (const float*)d_in[6];
  const float* Wc   = (const float*)d_in[7];
  const float* bc   = (const float*)d_in[8];
  const float* Wo   = (const float*)d_in[9];
  const float* bo   = (const float*)d_in[10];
  const float* Wout = (const float*)d_in[11];
  const float* bout = (const float*)d_in[12];
  float* out = (float*)d_out;

  char* ws = (char*)d_ws;
  const size_t HB = (size_t)NROW * HHP * sizeof(unsigned short);  // 198656
  unsigned short* hhi0 = (unsigned short*)(ws);
  unsigned short* hhi1 = (unsigned short*)(ws + HB);
  unsigned short* hhi2 = (unsigned short*)(ws + 2 * HB);
  unsigned*       bar  = (unsigned*)(ws + 3 * HB);
  unsigned short* dummy = (unsigned short*)(ws + 3 * HB + 4096);  // unused lo

  hipMemsetAsync(bar, 0, 4096, stream);    // zero barrier/rendezvous counters

  (void)in_sizes; (void)n_in; (void)out_size; (void)ws_size;
  hipLaunchKernelGGL(lstm_persistent, dim3(GR * GP), dim3(512), 0, stream,
                     xin, h0, c0, Wi, bi, Wf, bfv, Wc, bc, Wo, bo,
                     Wout, bout, out, hhi0, hhi1, hhi2, dummy, dummy, dummy, bar);
}

// Round 9
// 680.585 us; speedup vs baseline: 1.3089x; 1.0095x over previous
//
#include <hip/hip_runtime.h>

typedef float f32x4 __attribute__((ext_vector_type(4)));
typedef short s16x8 __attribute__((ext_vector_type(8)));
typedef unsigned uint4v __attribute__((ext_vector_type(4)));

#define HH   768
#define HHP  776   // h-buffer row pitch in shorts (GLOBAL and LDS identical)
#define SS   256
#define GR   8     // row groups (16 rows each); g = blockIdx & 7
#define GP   24    // col blocks per group; p = blockIdx >> 3
#define NROW 128
#define LDP  776   // LDS row pitch (shorts); 1552B = 16B-aligned rows
#define PP   68    // partials row pitch (floats)

__device__ __forceinline__ unsigned short f2bf(float f) {
  unsigned int u = __float_as_uint(f);
  u += 0x7FFFu + ((u >> 16) & 1u);          // RTNE
  return (unsigned short)(u >> 16);
}
__device__ __forceinline__ float bf2f(unsigned short s) {
  return __uint_as_float(((unsigned int)s) << 16);
}
__device__ __forceinline__ float sigm(float v) { return 1.0f / (1.0f + __expf(-v)); }
__device__ __forceinline__ float tanhf_(float v) {
  return 1.0f - 2.0f / (__expf(2.0f * v) + 1.0f);
}
// async global->LDS, 16B per lane; dest = wave-uniform base + lane*16 (HW).
__device__ __forceinline__ void gll16(const void* gp, void* lp) {
  __builtin_amdgcn_global_load_lds(
      (const __attribute__((address_space(1))) unsigned*)gp,
      (__attribute__((address_space(3))) unsigned*)lp, 16, 0, 0);
}

// 192 blocks x 512 threads (8 waves, 2/SIMD via launch_bounds(512,2)).
// Static roles: g = blockIdx&7 (rows [16g,16g+16)), p = blockIdx>>3 (hidden
// cols [32p,32p+32)); gate cols permuted col = hcol*4 + gate.
// Wave w: colh = w&1 (64-gate-col half), ks = w>>1 (6-kt slice of K).
// R12 (WIN 968->830): h transported bf16-only. R14 (neutral, kept): staging
// via global_load_lds w=16, pitch-776 identity copy. R15 (WIN 830->687,
// steady 624): W transported as single bf16 (Blo dropped) — 24 MFMA/wave.
// R16 (this round): loop-invariant hoisting (syncthreads blocks compiler
// hoisting, so do it by hand):
//  - bq/wq (bias + x-weight f32x4) LDS->registers, once.
//  - c state: thread<->cell map is fixed across all 256 steps and c is
//    never read by any other thread -> keep c in a REGISTER; c_lds is only
//    the one-time init handoff (init mapping != loop mapping).
//  - poll s_sleep(1) removed: dependent agent loads self-pace (~700cy RT).
// Bit-identical arithmetic; only residency changes.
// Barrier: R6-proven agent-scope counter otherwise VERBATIM. Closed dead
// ends (do not revisit): R8 flag-poll, R9 sc0-load poll (hang), R13 local
// RMW-poll (+60us), R10 direct-L2 A-frags (-32%), R11 split-phase staging
// (-18%), R14 staging DMA (neutral), wave-per-n-tile restructure (frag reads
// 48->192 b128 = +1700cy LDS port, rejected on paper).
__global__ void __launch_bounds__(512, 2) lstm_persistent(
    const float* __restrict__ xin, const float* __restrict__ h0,
    const float* __restrict__ c0,
    const float* __restrict__ Wi, const float* __restrict__ bi,
    const float* __restrict__ Wf, const float* __restrict__ bfv,
    const float* __restrict__ Wc, const float* __restrict__ bc,
    const float* __restrict__ Wo, const float* __restrict__ bo,
    const float* __restrict__ Wout, const float* __restrict__ bout,
    float* __restrict__ out,
    unsigned short* __restrict__ hhi0, unsigned short* __restrict__ hhi1,
    unsigned short* __restrict__ hhi2,
    unsigned short* __restrict__ hlo0, unsigned short* __restrict__ hlo1,
    unsigned short* __restrict__ hlo2,
    unsigned* __restrict__ bar)
{
  const int tid = threadIdx.x, wave = tid >> 6, lane = tid & 63;
  const int l15 = lane & 15, quad = lane >> 4;
  const int g = blockIdx.x & 7, p = blockIdx.x >> 3;
  const int row_base = g * 16, hcol_base = p * 32;
  const int colh = wave & 1, ks = wave >> 1;   // col-half / kt-slice

  __shared__ __align__(16) unsigned short lds_hi[16 * LDP];
  __shared__ __align__(16) float part[2][4][16][PP];   // [colh][ks][row][col64]
  __shared__ float bw_b[128], bw_w[128];               // bias / x-weight per col
  __shared__ float c_lds[16][33];                      // init handoff only
  __shared__ float x_lds[16];
  __shared__ int s_fast;

  unsigned* ctr = bar + g * 64;              // step barrier (256B-spaced)
  unsigned* rdy = bar + 512 + g * 16;        // rendezvous counter
  unsigned* ids = bar + 640 + g * 32;        // 24 published XCC_IDs

  // ---- one-time vote (tid0): all 24 members on one XCD? [R6-proven] ----
  if (tid == 0) {
    const unsigned my = (__builtin_amdgcn_s_getreg(20 | (3 << 11)) & 15u) + 1u;
    __hip_atomic_store(ids + p, my, __ATOMIC_RELAXED, __HIP_MEMORY_SCOPE_AGENT);
    __hip_atomic_fetch_add(rdy, 1u, __ATOMIC_RELEASE, __HIP_MEMORY_SCOPE_AGENT);
    while (__hip_atomic_load(rdy, __ATOMIC_ACQUIRE, __HIP_MEMORY_SCOPE_AGENT)
           < (unsigned)GP)
      __builtin_amdgcn_s_sleep(8);
    int ok = 1;
    for (int q = 0; q < GP; ++q)
      ok &= (__hip_atomic_load(ids + q, __ATOMIC_RELAXED,
                               __HIP_MEMORY_SCOPE_AGENT) == my);
    s_fast = ok;
  }

  // ---- one-time: weights -> bf16 hi B-fragments (n=lane&15, k=quad*8+j) --
  s16x8 Bhi[6][4];
#pragma unroll
  for (int n = 0; n < 4; ++n) {
    const int col = p * 128 + colh * 64 + n * 16 + l15;  // permuted gate col
    const int gg = col & 3, hc = col >> 2;
    const float* W = (gg == 0) ? Wi : (gg == 1) ? Wf : (gg == 2) ? Wc : Wo;
#pragma unroll
    for (int ktl = 0; ktl < 6; ++ktl) {
      const int kt = ks * 6 + ktl;
      s16x8 vh;
#pragma unroll
      for (int j = 0; j < 8; ++j) {
        const int k = kt * 32 + quad * 8 + j;
        vh[j] = (short)f2bf(W[(1 + k) * HH + hc]);
      }
      Bhi[ktl][n] = vh;
    }
  }

  // ---- one-time: bias + x-weight tables -> LDS (per permuted gate col) ----
  if (tid < 128) {
    const int gg = tid & 3;
    const int hc = p * 32 + (tid >> 2);
    const float* W  = (gg == 0) ? Wi : (gg == 1) ? Wf : (gg == 2) ? Wc : Wo;
    const float* bb = (gg == 0) ? bi : (gg == 1) ? bfv : (gg == 2) ? bc : bo;
    bw_b[tid] = bb[hc];
    bw_w[tid] = W[hc];                       // W row 0 = x weight (exact fp32)
  }

  // ---- init: c->LDS; h0 -> parity-0 hi buffer (agent stores, pitch 776) --
  if (tid < 256) {
    const int lr = tid >> 4, lc = (tid & 15) * 2;
    const int gidx = (row_base + lr) * HH + hcol_base + lc;    // input (768)
    const int sidx = (row_base + lr) * HHP + hcol_base + lc;   // buffer (776)
    const float ha = h0[gidx], hb = h0[gidx + 1];
    c_lds[lr][lc]     = c0[gidx];
    c_lds[lr][lc + 1] = c0[gidx + 1];
    const unsigned short ha_hi = f2bf(ha), hb_hi = f2bf(hb);
    __hip_atomic_store((unsigned*)hhi0 + (sidx >> 1),
                       (unsigned)ha_hi | ((unsigned)hb_hi << 16),
                       __ATOMIC_RELAXED, __HIP_MEMORY_SCOPE_AGENT);
    if (tid < 16) {
      const int row = row_base + tid;
      x_lds[tid] = xin[(row >> 1) * (SS * 2) + (row & 1)];   // t = 0
    }
  }
  __syncthreads();                           // s_fast + LDS init visible
  const bool fast = (s_fast != 0);
  unsigned bars = 0;

  // Agent-scope counter barrier (R3/R6-proven; poll sleep removed — the
  // ~700cy dependent-load RT self-paces; R8/R9/R13 variants failed).
  auto gbar = [&]() {
    __builtin_amdgcn_s_waitcnt(0);
    __syncthreads();
    if (tid == 0) {
      ++bars;
      __hip_atomic_fetch_add(ctr, 1u, __ATOMIC_RELAXED, __HIP_MEMORY_SCOPE_AGENT);
      const unsigned want = (unsigned)GP * bars;
      while (__hip_atomic_load(ctr, __ATOMIC_RELAXED, __HIP_MEMORY_SCOPE_AGENT) < want) {}
    }
    __syncthreads();
  };

  // ---- hoisted loop invariants (compiler can't hoist across barriers) ----
  const int lr_c = tid >> 5, lc_c = tid & 31;        // elementwise cell
  const int ch_c = lc_c >> 4, c4_c = (lc_c & 15) * 4;
  const f32x4 bq = *(const f32x4*)&bw_b[lc_c * 4];   // bias (4 gates of cell)
  const f32x4 wq = *(const f32x4*)&bw_w[lc_c * 4];   // x-weight (4 gates)
  float cc_reg = c_lds[lr_c][lc_c];                  // c state: REGISTER from
                                                     // here on (thread-private
                                                     // for all 256 steps)
  gbar();                                    // h0/c0 published

  const unsigned short* hbhi[3] = {hhi0, hhi1, hhi2};
  unsigned short* wbhi[3] = {hhi0, hhi1, hhi2};

  const int frag_off = l15 * LDP + quad * 8; // A-frag LDS offset (shorts)
  const int wbase = wave * 64;               // wave-uniform lane base
  int cur = 0;

  for (int t = 0; t < SS; ++t) {
    const int nxt = (cur == 2) ? 0 : cur + 1;
    const unsigned short* rhi = hbhi[cur];
    unsigned short* whi = wbhi[nxt];

    // ---- stage group h-slice: identity copy 16 x 776 shorts (24832B) ----
    if (fast) {                              // async global->LDS, no VGPR trip
      const unsigned short* src = rhi + row_base * HHP;
#pragma unroll
      for (int i = 0; i < 3; ++i) {
        const int gi = i * 512 + tid;        // u128 idx (per-lane global src)
        gll16(src + gi * 8, &lds_hi[(i * 512 + wbase) * 8]);
      }
      if (tid < 16) {                        // tail u128s 1536..1551 (plain)
        const uint4v v = *(const uint4v*)(src + (1536 + tid) * 8);
        *(uint4v*)&lds_hi[(1536 + tid) * 8] = v;
      }
    } else {                                 // agent-scope (MALL) identity copy
      const unsigned long long* src64 =
          (const unsigned long long*)rhi + row_base * (HHP / 4);
#pragma unroll
      for (int i = 0; i < 6; ++i) {
        const int gi = i * 512 + tid;        // u64 idx in [0,3072)
        const unsigned long long vh = __hip_atomic_load(
            src64 + gi, __ATOMIC_RELAXED, __HIP_MEMORY_SCOPE_AGENT);
        *(unsigned long long*)&lds_hi[gi * 4] = vh;
      }
      if (tid < 32) {                        // tail u64s 3072..3103
        const int gi = 3072 + tid;
        const unsigned long long vh = __hip_atomic_load(
            src64 + gi, __ATOMIC_RELAXED, __HIP_MEMORY_SCOPE_AGENT);
        *(unsigned long long*)&lds_hi[gi * 4] = vh;
      }
    }
    __syncthreads();                         // drains vmcnt (gll) + lgkm

    // ---- GEMM: wave (colh,ks): 6kt x 4n, 1 MFMA/(ktl,n): h_hi*W_hi ----
    f32x4 acc[4] = {{0,0,0,0},{0,0,0,0},{0,0,0,0},{0,0,0,0}};
#pragma unroll
    for (int ktl = 0; ktl < 6; ++ktl) {
      const int kt = ks * 6 + ktl;
      const s16x8 ah = *(const s16x8*)&lds_hi[frag_off + kt * 32];
#pragma unroll
      for (int n = 0; n < 4; ++n)
        acc[n] = __builtin_amdgcn_mfma_f32_16x16x32_bf16(ah, Bhi[ktl][n], acc[n], 0, 0, 0);
    }

    // ---- partial write: C/D layout col=l15, row=quad*4+reg ----
#pragma unroll
    for (int n = 0; n < 4; ++n)
#pragma unroll
      for (int reg = 0; reg < 4; ++reg)
        part[colh][ks][quad * 4 + reg][n * 16 + l15] = acc[n][reg];
    __syncthreads();

    // ---- reduce over ks + bias + x*w0; elementwise; h store (1 cell/thr) --
    {
      const f32x4 s0 = *(const f32x4*)&part[ch_c][0][lr_c][c4_c];
      const f32x4 s1 = *(const f32x4*)&part[ch_c][1][lr_c][c4_c];
      const f32x4 s2 = *(const f32x4*)&part[ch_c][2][lr_c][c4_c];
      const f32x4 s3 = *(const f32x4*)&part[ch_c][3][lr_c][c4_c];
      const float xv = x_lds[lr_c];
      f32x4 gv = (s0 + s1) + (s2 + s3);
#pragma unroll
      for (int j = 0; j < 4; ++j) gv[j] += bq[j] + xv * wq[j];

      cc_reg = sigm(gv[1]) * cc_reg + sigm(gv[0]) * tanhf_(gv[2]);
      const float hh = gv[3] * tanhf_(cc_reg);  // no sigmoid on o-gate (ref)

      const unsigned short mhi = f2bf(hh);
      const unsigned ohi = (unsigned)__shfl_down((int)(unsigned)mhi, 1, 64);
      if ((tid & 1) == 0) {                  // lc_c even; neighbor = lc_c+1
        const int sidx = (row_base + lr_c) * HHP + hcol_base + lc_c;
        const unsigned ph = (unsigned)mhi | (ohi << 16);
        if (fast) {                          // write-through L1 -> XCD L2
          ((unsigned*)whi)[sidx >> 1] = ph;
        } else {
          __hip_atomic_store((unsigned*)whi + (sidx >> 1), ph, __ATOMIC_RELAXED, __HIP_MEMORY_SCOPE_AGENT);
        }
      }
      if (tid < 16 && t + 1 < SS) {
        const int row = row_base + tid;
        x_lds[tid] = xin[(row >> 1) * (SS * 2) + (t + 1) * 2 + (row & 1)];
      }
    }
    gbar();
    cur = nxt;
  }

  // ---- output projection: final h in parity cur = 256%3 = 1 ----
  if (p == 0 && tid < 256) {
    const unsigned short* fhi = hbhi[cur];
    const int rloc = tid >> 4, s = tid & 15;
    const int row = row_base + rloc;
    float sum = 0.0f;
#pragma unroll
    for (int i = 0; i < 12; ++i) {
      const int u = row * (HHP / 4) + s * 12 + i;  // u64 idx; k0 = s*48 + i*4
      unsigned long long vh;
      if (fast) {                            // fresh in this XCD's L2
        vh = *((const unsigned long long*)fhi + u);
      } else {
        vh = __hip_atomic_load((unsigned long long*)fhi + u, __ATOMIC_RELAXED, __HIP_MEMORY_SCOPE_AGENT);
      }
#pragma unroll
      for (int j = 0; j < 4; ++j) {
        const float h = bf2f((unsigned short)(vh >> (16 * j)));
        sum += h * Wout[s * 48 + i * 4 + j];
      }
    }
#pragma unroll
    for (int off = 8; off; off >>= 1) sum += __shfl_down(sum, off, 16);
    if (s == 0) out[row] = sum + bout[0];
  }
}

extern "C" void kernel_launch(void* const* d_in, const int* in_sizes, int n_in,
                              void* d_out, int out_size, void* d_ws, size_t ws_size,
                              hipStream_t stream) {
  const float* xin  = (const float*)d_in[0];
  const float* h0   = (const float*)d_in[1];
  const float* c0   = (const float*)d_in[2];
  const float* Wi   = (const float*)d_in[3];
  const float* bi   = (const float*)d_in[4];
  const float* Wf   = (const float*)d_in[5];
  const float* bfv  = (const float*)d_in[6];
  const float* Wc   = (const float*)d_in[7];
  const float* bc   = (const float*)d_in[8];
  const float* Wo   = (const float*)d_in[9];
  const float* bo   = (const float*)d_in[10];
  const float* Wout = (const float*)d_in[11];
  const float* bout = (const float*)d_in[12];
  float* out = (float*)d_out;

  char* ws = (char*)d_ws;
  const size_t HB = (size_t)NROW * HHP * sizeof(unsigned short);  // 198656
  unsigned short* hhi0 = (unsigned short*)(ws);
  unsigned short* hhi1 = (unsigned short*)(ws + HB);
  unsigned short* hhi2 = (unsigned short*)(ws + 2 * HB);
  unsigned*       bar  = (unsigned*)(ws + 3 * HB);
  unsigned short* dummy = (unsigned short*)(ws + 3 * HB + 4096);  // unused lo

  hipMemsetAsync(bar, 0, 4096, stream);    // zero barrier/rendezvous counters

  (void)in_sizes; (void)n_in; (void)out_size; (void)ws_size;
  hipLaunchKernelGGL(lstm_persistent, dim3(GR * GP), dim3(512), 0, stream,
                     xin, h0, c0, Wi, bi, Wf, bfv, Wc, bc, Wo, bo,
                     Wout, bout, out, hhi0, hhi1, hhi2, dummy, dummy, dummy, bar);
}